// Round 3
// baseline (102.129 us; speedup 1.0000x reference)
//
#include <hip/hip_runtime.h>
#include <hip/hip_bf16.h>

typedef __bf16 bf16x8 __attribute__((ext_vector_type(8)));
typedef float  f32x4  __attribute__((ext_vector_type(4)));

#define HW       3136
#define IMG_W    56
#define IMG_H    56
#define XT_ROW_B 16384                     // 64 cols * 128ch * 2B
#define XT_IMG_B (58*XT_ROW_B)             // 950272
#define XT_BYTES ((size_t)32*XT_IMG_B)     // ~30.4 MB
#define WELEMS   (9*128*128)
#define WB_BYTES ((size_t)WELEMS*2)
#define NBLK     896                       // 32 img * 28 row-pairs
#define PBLK     (32*58)                   // prepass blocks

// ---- weight fp32 -> bf16 ----
__global__ __launch_bounds__(256) void wcvt_kernel(const float* __restrict__ w,
                                                   __bf16* __restrict__ wb, int n) {
    int i = blockIdx.x * 256 + threadIdx.x;
    if (i < n) wb[i] = (__bf16)w[i];
}

// ---- prepass: x [n][c][h][w] fp32 -> xt [n][58][64][128] bf16,
//      zero borders, XOR swizzle ((col&7) granules) baked into layout ----
__global__ __launch_bounds__(256) void xprep_kernel(const float* __restrict__ x,
                                                    unsigned char* __restrict__ xt) {
    __shared__ float ldsF[128 * 65];
    const int bid = blockIdx.x;
    const int swz = (bid & 7) * (PBLK / 8) + (bid >> 3);
    const int n = swz / 58, rt = swz - n * 58;
    unsigned char* row = xt + (size_t)n * XT_IMG_B + (size_t)rt * XT_ROW_B;
    const int t = threadIdx.x;

    if (rt == 0 || rt == 57) {            // zero border rows
        f32x4 z = {0.f, 0.f, 0.f, 0.f};
        #pragma unroll
        for (int i = 0; i < 4; ++i) *(f32x4*)(row + t * 64 + i * 16) = z;
        return;
    }
    const int r = rt - 1;
    const float* xr = x + (size_t)n * 128 * HW + (size_t)r * IMG_W;
    const int wv = t >> 6, lane = t & 63;
    const int wi = min(lane, IMG_W - 1);
    #pragma unroll
    for (int cc = 0; cc < 32; ++cc) {
        int c = cc * 4 + wv;
        float v = xr[(size_t)c * HW + wi];
        ldsF[c * 65 + lane] = (lane < IMG_W) ? v : 0.f;
    }
    __syncthreads();

    const int cl = t >> 2, q = t & 3;     // col 0..63, channel quarter
    const bool inb = (cl >= 1) && (cl <= 56);
    #pragma unroll
    for (int g4 = 0; g4 < 4; ++g4) {
        int gi = q * 4 + g4;              // granule = channels gi*8..gi*8+7
        bf16x8 pk;
        #pragma unroll
        for (int j = 0; j < 8; ++j)
            pk[j] = inb ? (__bf16)ldsF[(gi * 8 + j) * 65 + (cl - 1)] : (__bf16)0.0f;
        *(bf16x8*)(row + cl * 256 + ((gi ^ (cl & 7)) * 16)) = pk;
    }
}

// ---- conv: one wave = 64 oc x NPF*16 positions ----
template<int NPF>
__device__ __forceinline__ void compute_store(const unsigned char* xs, const __bf16* wb,
                                              float* on, int oc0, int pf0, int r0, int lane) {
    const int l15 = lane & 15, lq = lane >> 4;
    int rowb[NPF], scol[NPF], p_[NPF];
    #pragma unroll
    for (int k = 0; k < NPF; ++k) {
        int p = (pf0 + k) * 16 + l15;     // 0..111 block-local pos
        int pr = p / 56, pc = p - pr * 56;
        p_[k] = p;
        rowb[k] = (pr + 1) * 64 + (pc + 1);
        scol[k] = pc + 1;
    }
    f32x4 acc[4][NPF];
    #pragma unroll
    for (int f = 0; f < 4; ++f)
        #pragma unroll
        for (int k = 0; k < NPF; ++k) acc[f][k] = (f32x4){0.f, 0.f, 0.f, 0.f};

    #pragma unroll
    for (int tap = 0; tap < 9; ++tap) {
        const int dh = tap / 3 - 1, dw = tap - (tap / 3) * 3 - 1;
        // hoist all 16 A-fragments for this tap (64 VGPR)
        bf16x8 a[4][4];
        const __bf16* wt = wb + tap * 16384 + (oc0 + l15) * 128 + lq * 8;
        #pragma unroll
        for (int f = 0; f < 4; ++f)
            #pragma unroll
            for (int c = 0; c < 4; ++c) a[f][c] = *(const bf16x8*)(wt + f * 2048 + c * 32);

        int base[NPF], sw[NPF];
        #pragma unroll
        for (int k = 0; k < NPF; ++k) {
            base[k] = (rowb[k] + dh * 64 + dw) * 256;
            sw[k]   = (scol[k] + dw) & 7;
        }
        #pragma unroll
        for (int c = 0; c < 4; ++c) {
            #pragma unroll
            for (int k = 0; k < NPF; ++k) {
                int gi = (c * 4 + lq) ^ sw[k];
                bf16x8 b = *(const bf16x8*)(xs + base[k] + gi * 16);
                #pragma unroll
                for (int f = 0; f < 4; ++f)
                    acc[f][k] = __builtin_amdgcn_mfma_f32_16x16x32_bf16(a[f][c], b, acc[f][k], 0, 0, 0);
            }
        }
    }
    #pragma unroll
    for (int f = 0; f < 4; ++f)
        #pragma unroll
        for (int k = 0; k < NPF; ++k) {
            int pos = r0 * 56 + p_[k];
            int oc  = oc0 + f * 16 + lq * 4;
            #pragma unroll
            for (int rr = 0; rr < 4; ++rr)
                on[(size_t)(oc + rr) * HW + pos] = acc[f][k][rr];
        }
}

__global__ __launch_bounds__(256, 2) void conv_kernel(const unsigned char* __restrict__ xt,
                                                      const __bf16* __restrict__ wb,
                                                      float* __restrict__ out) {
    __shared__ __align__(16) unsigned char xs[65536];   // 4 rows x 64 cols x 256B
    const int t = threadIdx.x, lane = t & 63, wv = t >> 6;
    const int bid = blockIdx.x;
    const int swz = (bid & 7) * (NBLK / 8) + (bid >> 3);
    const int n = swz / 28, rp = swz - n * 28, r0 = rp * 2;

    // async linear 64KB copy: xt rows r0..r0+3 (contiguous) -> LDS
    const unsigned char* src = xt + (size_t)n * XT_IMG_B + (size_t)r0 * XT_ROW_B;
    #pragma unroll
    for (int i = 0; i < 16; ++i) {
        __builtin_amdgcn_global_load_lds(
            (const __attribute__((address_space(1))) unsigned int*)(src + i * 4096 + t * 16),
            (__attribute__((address_space(3))) unsigned int*)(xs + i * 4096 + wv * 1024),
            16, 0, 0);
    }
    __syncthreads();

    const int oc0 = (wv & 1) * 64;
    float* on = out + (size_t)n * 128 * HW;
    if (wv < 2) compute_store<4>(xs, wb, on, oc0, 0, r0, lane);
    else        compute_store<3>(xs, wb, on, oc0, 4, r0, lane);
}

// ================= fallback (ws too small): round-2 kernel, fp32 weights =================
#define PITCH  272
#define LDSB   (4*64*PITCH)

template<int NPF>
__device__ __forceinline__ void fb_compute(const unsigned char* xs, const float* wf,
                                           float* on, int oc0, int pf0, int r0, int lane) {
    const int l15 = lane & 15, lq = lane >> 4;
    int spb[NPF];
    #pragma unroll
    for (int k = 0; k < NPF; ++k) {
        int p = (pf0 + k) * 16 + l15;
        int r = p / 56, w = p - r * 56;
        spb[k] = ((r + 1) * 64 + (w + 1)) * PITCH + lq * 16;
    }
    f32x4 acc[4][NPF];
    #pragma unroll
    for (int f = 0; f < 4; ++f)
        #pragma unroll
        for (int k = 0; k < NPF; ++k) acc[f][k] = (f32x4){0.f, 0.f, 0.f, 0.f};
    #pragma unroll 3
    for (int tap = 0; tap < 9; ++tap) {
        const int offb  = ((tap / 3) * 64 + (tap % 3) - 65) * PITCH;
        const int wbase = tap * 16384 + oc0 * 128 + l15 * 128 + lq * 8;
        #pragma unroll
        for (int c = 0; c < 4; ++c) {
            bf16x8 a[4];
            #pragma unroll
            for (int f = 0; f < 4; ++f) {
                const float* p = wf + wbase + f * 2048 + c * 32;
                #pragma unroll
                for (int j = 0; j < 8; ++j) a[f][j] = (__bf16)p[j];
            }
            #pragma unroll
            for (int k = 0; k < NPF; ++k) {
                bf16x8 b = *(const bf16x8*)(xs + spb[k] + offb + c * 64);
                #pragma unroll
                for (int f = 0; f < 4; ++f)
                    acc[f][k] = __builtin_amdgcn_mfma_f32_16x16x32_bf16(a[f], b, acc[f][k], 0, 0, 0);
            }
        }
    }
    #pragma unroll
    for (int f = 0; f < 4; ++f)
        #pragma unroll
        for (int k = 0; k < NPF; ++k) {
            int pos = r0 * 56 + (pf0 + k) * 16 + l15;
            int oc  = oc0 + f * 16 + lq * 4;
            #pragma unroll
            for (int rr = 0; rr < 4; ++rr)
                on[(size_t)(oc + rr) * HW + pos] = acc[f][k][rr];
        }
}

__global__ __launch_bounds__(256, 2) void fb_conv_kernel(const float* __restrict__ x,
                                                         const float* __restrict__ wf,
                                                         float* __restrict__ out) {
    __shared__ __align__(16) unsigned char xs[LDSB];
    const int tid = threadIdx.x, lane = tid & 63, wv = tid >> 6;
    const int bid = blockIdx.x;
    const int swz = (bid & 7) * (NBLK / 8) + (bid >> 3);
    const int n = swz / 28, rp = swz - n * 28, r0 = rp * 2;
    {
        const float* xn = x + (size_t)n * 128 * HW;
        const int ar = r0 - 1 + wv, wi = lane - 1;
        const bool v = (ar >= 0) & (ar < IMG_H) & (wi >= 0) & (wi < IMG_W);
        const int gc = min(max(ar, 0), IMG_H - 1) * IMG_W + min(max(wi, 0), IMG_W - 1);
        unsigned char* dst = xs + (wv * 64 + lane) * PITCH;
        #pragma unroll
        for (int cg = 0; cg < 16; ++cg) {
            bf16x8 pk;
            #pragma unroll
            for (int j = 0; j < 8; ++j) {
                float f = xn[(size_t)(cg * 8 + j) * HW + gc];
                pk[j] = (__bf16)(v ? f : 0.f);
            }
            *(bf16x8*)(dst + cg * 16) = pk;
        }
    }
    __syncthreads();
    const int oc0 = (wv & 1) * 64;
    float* on = out + (size_t)n * 128 * HW;
    if (wv < 2) fb_compute<4>(xs, wf, on, oc0, 0, r0, lane);
    else        fb_compute<3>(xs, wf, on, oc0, 4, r0, lane);
}

extern "C" void kernel_launch(void* const* d_in, const int* in_sizes, int n_in,
                              void* d_out, int out_size, void* d_ws, size_t ws_size,
                              hipStream_t stream) {
    const float* x = (const float*)d_in[0];
    const float* w = (const float*)d_in[1];
    float* out = (float*)d_out;

    if (ws_size >= XT_BYTES + WB_BYTES) {
        unsigned char* xt = (unsigned char*)d_ws;
        __bf16* wb = (__bf16*)(xt + XT_BYTES);
        wcvt_kernel<<<(WELEMS + 255) / 256, 256, 0, stream>>>(w, wb, WELEMS);
        xprep_kernel<<<PBLK, 256, 0, stream>>>(x, xt);
        conv_kernel<<<NBLK, 256, 0, stream>>>(xt, wb, out);
    } else {
        fb_conv_kernel<<<NBLK, 256, 0, stream>>>(x, w, out);
    }
}

// Round 4
// 99.876 us; speedup vs baseline: 1.0226x; 1.0226x over previous
//
#include <hip/hip_runtime.h>
#include <hip/hip_bf16.h>

typedef __bf16 bf16x8 __attribute__((ext_vector_type(8)));
typedef float  f32x4  __attribute__((ext_vector_type(4)));

#define HW       3136
#define IMG_W    56
#define IMG_H    56
#define XT_ROW_B 16384                     // 64 cols * 128ch * 2B
#define XT_IMG_B (58*XT_ROW_B)             // 950272
#define XT_BYTES ((size_t)32*XT_IMG_B)     // ~30.4 MB
#define WELEMS   (9*128*128)
#define WB_BYTES ((size_t)WELEMS*2)
#define NBLK     896                       // 32 img * 28 row-pairs
#define PBLK     (32*58)                   // prepass blocks

// ---- weight fp32 -> bf16 ----
__global__ __launch_bounds__(256) void wcvt_kernel(const float* __restrict__ w,
                                                   __bf16* __restrict__ wb, int n) {
    int i = blockIdx.x * 256 + threadIdx.x;
    if (i < n) wb[i] = (__bf16)w[i];
}

// ---- prepass: x [n][c][h][w] fp32 -> xt [n][58][64][128] bf16,
//      zero borders, XOR swizzle ((col&7) granules) baked into layout ----
__global__ __launch_bounds__(256) void xprep_kernel(const float* __restrict__ x,
                                                    unsigned char* __restrict__ xt) {
    __shared__ float ldsF[128 * 65];
    const int bid = blockIdx.x;
    const int swz = (bid & 7) * (PBLK / 8) + (bid >> 3);
    const int n = swz / 58, rt = swz - n * 58;
    unsigned char* row = xt + (size_t)n * XT_IMG_B + (size_t)rt * XT_ROW_B;
    const int t = threadIdx.x;

    if (rt == 0 || rt == 57) {            // zero border rows
        f32x4 z = {0.f, 0.f, 0.f, 0.f};
        #pragma unroll
        for (int i = 0; i < 4; ++i) *(f32x4*)(row + t * 64 + i * 16) = z;
        return;
    }
    const int r = rt - 1;
    const float* xr = x + (size_t)n * 128 * HW + (size_t)r * IMG_W;
    const int wv = t >> 6, lane = t & 63;
    const int wi = min(lane, IMG_W - 1);
    #pragma unroll
    for (int cc = 0; cc < 32; ++cc) {
        int c = cc * 4 + wv;
        float v = xr[(size_t)c * HW + wi];
        ldsF[c * 65 + lane] = (lane < IMG_W) ? v : 0.f;
    }
    __syncthreads();

    const int cl = t >> 2, q = t & 3;     // col 0..63, channel quarter
    const bool inb = (cl >= 1) && (cl <= 56);
    #pragma unroll
    for (int g4 = 0; g4 < 4; ++g4) {
        int gi = q * 4 + g4;              // granule = channels gi*8..gi*8+7
        bf16x8 pk;
        #pragma unroll
        for (int j = 0; j < 8; ++j)
            pk[j] = inb ? (__bf16)ldsF[(gi * 8 + j) * 65 + (cl - 1)] : (__bf16)0.0f;
        *(bf16x8*)(row + cl * 256 + ((gi ^ (cl & 7)) * 16)) = pk;
    }
}

// ---- conv: one wave = 32 oc x NPF*16 positions (low register pressure) ----
template<int NPF>
__device__ __forceinline__ void compute_store(const unsigned char* xs, const __bf16* wb,
                                              float* on, int oc0, int pf0, int r0, int lane) {
    const int l15 = lane & 15, lq = lane >> 4;
    int rowb[NPF], scol[NPF], p_[NPF];
    #pragma unroll
    for (int k = 0; k < NPF; ++k) {
        int p = (pf0 + k) * 16 + l15;     // 0..111 block-local pos
        int pr = p / 56, pc = p - pr * 56;
        p_[k] = p;
        rowb[k] = (pr + 1) * 64 + (pc + 1);
        scol[k] = pc + 1;
    }
    f32x4 acc[2][NPF];
    #pragma unroll
    for (int f = 0; f < 2; ++f)
        #pragma unroll
        for (int k = 0; k < NPF; ++k) acc[f][k] = (f32x4){0.f, 0.f, 0.f, 0.f};

    #pragma unroll
    for (int tap = 0; tap < 9; ++tap) {
        const int dh = tap / 3 - 1, dw = tap - (tap / 3) * 3 - 1;
        // hoist 8 A-fragments for this tap (32 VGPR)
        bf16x8 a[2][4];
        const __bf16* wt = wb + tap * 16384 + (oc0 + l15) * 128 + lq * 8;
        #pragma unroll
        for (int f = 0; f < 2; ++f)
            #pragma unroll
            for (int c = 0; c < 4; ++c) a[f][c] = *(const bf16x8*)(wt + f * 2048 + c * 32);

        int base[NPF], sw[NPF];
        #pragma unroll
        for (int k = 0; k < NPF; ++k) {
            base[k] = (rowb[k] + dh * 64 + dw) * 256;
            sw[k]   = (scol[k] + dw) & 7;
        }
        #pragma unroll
        for (int c = 0; c < 4; ++c) {
            #pragma unroll
            for (int k = 0; k < NPF; ++k) {
                int gi = (c * 4 + lq) ^ sw[k];
                bf16x8 b = *(const bf16x8*)(xs + base[k] + gi * 16);
                #pragma unroll
                for (int f = 0; f < 2; ++f)
                    acc[f][k] = __builtin_amdgcn_mfma_f32_16x16x32_bf16(a[f][c], b, acc[f][k], 0, 0, 0);
            }
        }
    }
    #pragma unroll
    for (int f = 0; f < 2; ++f)
        #pragma unroll
        for (int k = 0; k < NPF; ++k) {
            int pos = r0 * 56 + p_[k];
            int oc  = oc0 + f * 16 + lq * 4;
            #pragma unroll
            for (int rr = 0; rr < 4; ++rr)
                on[(size_t)(oc + rr) * HW + pos] = acc[f][k][rr];
        }
}

__global__ __launch_bounds__(512, 4) void conv_kernel(const unsigned char* __restrict__ xt,
                                                      const __bf16* __restrict__ wb,
                                                      float* __restrict__ out) {
    __shared__ __align__(16) unsigned char xs[65536];   // 4 rows x 64 cols x 256B
    const int t = threadIdx.x, lane = t & 63, wv = t >> 6;   // 8 waves
    const int bid = blockIdx.x;
    const int swz = (bid & 7) * (NBLK / 8) + (bid >> 3);
    const int n = swz / 28, rp = swz - n * 28, r0 = rp * 2;

    // async linear 64KB copy: xt rows r0..r0+3 (contiguous) -> LDS
    const unsigned char* src = xt + (size_t)n * XT_IMG_B + (size_t)r0 * XT_ROW_B;
    #pragma unroll
    for (int i = 0; i < 8; ++i) {
        __builtin_amdgcn_global_load_lds(
            (const __attribute__((address_space(1))) unsigned int*)(src + i * 8192 + t * 16),
            (__attribute__((address_space(3))) unsigned int*)(xs + i * 8192 + wv * 1024),
            16, 0, 0);
    }
    __syncthreads();

    // wave -> 32-oc quarter x pos-frag group: waves 0-3 frags 0-3, waves 4-7 frags 4-6
    const int oc0 = (wv & 3) * 32;
    float* on = out + (size_t)n * 128 * HW;
    if (wv < 4) compute_store<4>(xs, wb, on, oc0, 0, r0, lane);
    else        compute_store<3>(xs, wb, on, oc0, 4, r0, lane);
}

// ================= fallback (ws too small): self-contained, fp32 weights =================
#define PITCH  272
#define LDSB   (4*64*PITCH)

template<int NPF>
__device__ __forceinline__ void fb_compute(const unsigned char* xs, const float* wf,
                                           float* on, int oc0, int pf0, int r0, int lane) {
    const int l15 = lane & 15, lq = lane >> 4;
    int spb[NPF];
    #pragma unroll
    for (int k = 0; k < NPF; ++k) {
        int p = (pf0 + k) * 16 + l15;
        int r = p / 56, w = p - r * 56;
        spb[k] = ((r + 1) * 64 + (w + 1)) * PITCH + lq * 16;
    }
    f32x4 acc[2][NPF];
    #pragma unroll
    for (int f = 0; f < 2; ++f)
        #pragma unroll
        for (int k = 0; k < NPF; ++k) acc[f][k] = (f32x4){0.f, 0.f, 0.f, 0.f};
    #pragma unroll 3
    for (int tap = 0; tap < 9; ++tap) {
        const int offb  = ((tap / 3) * 64 + (tap % 3) - 65) * PITCH;
        const int wbase = tap * 16384 + oc0 * 128 + l15 * 128 + lq * 8;
        #pragma unroll
        for (int c = 0; c < 4; ++c) {
            bf16x8 a[2];
            #pragma unroll
            for (int f = 0; f < 2; ++f) {
                const float* p = wf + wbase + f * 2048 + c * 32;
                #pragma unroll
                for (int j = 0; j < 8; ++j) a[f][j] = (__bf16)p[j];
            }
            #pragma unroll
            for (int k = 0; k < NPF; ++k) {
                bf16x8 b = *(const bf16x8*)(xs + spb[k] + offb + c * 64);
                #pragma unroll
                for (int f = 0; f < 2; ++f)
                    acc[f][k] = __builtin_amdgcn_mfma_f32_16x16x32_bf16(a[f], b, acc[f][k], 0, 0, 0);
            }
        }
    }
    #pragma unroll
    for (int f = 0; f < 2; ++f)
        #pragma unroll
        for (int k = 0; k < NPF; ++k) {
            int pos = r0 * 56 + (pf0 + k) * 16 + l15;
            int oc  = oc0 + f * 16 + lq * 4;
            #pragma unroll
            for (int rr = 0; rr < 4; ++rr)
                on[(size_t)(oc + rr) * HW + pos] = acc[f][k][rr];
        }
}

__global__ __launch_bounds__(512, 4) void fb_conv_kernel(const float* __restrict__ x,
                                                         const float* __restrict__ wf,
                                                         float* __restrict__ out) {
    __shared__ __align__(16) unsigned char xs[LDSB];
    const int tid = threadIdx.x, lane = tid & 63, wv = tid >> 6;
    const int bid = blockIdx.x;
    const int swz = (bid & 7) * (NBLK / 8) + (bid >> 3);
    const int n = swz / 28, rp = swz - n * 28, r0 = rp * 2;
    if (wv < 4) {
        const float* xn = x + (size_t)n * 128 * HW;
        const int ar = r0 - 1 + wv, wi = lane - 1;
        const bool v = (ar >= 0) & (ar < IMG_H) & (wi >= 0) & (wi < IMG_W);
        const int gc = min(max(ar, 0), IMG_H - 1) * IMG_W + min(max(wi, 0), IMG_W - 1);
        unsigned char* dst = xs + (wv * 64 + lane) * PITCH;
        #pragma unroll
        for (int cg = 0; cg < 16; ++cg) {
            bf16x8 pk;
            #pragma unroll
            for (int j = 0; j < 8; ++j) {
                float f = xn[(size_t)(cg * 8 + j) * HW + gc];
                pk[j] = (__bf16)(v ? f : 0.f);
            }
            *(bf16x8*)(dst + cg * 16) = pk;
        }
    }
    __syncthreads();
    const int oc0 = (wv & 3) * 32;
    float* on = out + (size_t)n * 128 * HW;
    if (wv < 4) fb_compute<4>(xs, wf, on, oc0, 0, r0, lane);
    else        fb_compute<3>(xs, wf, on, oc0, 4, r0, lane);
}

extern "C" void kernel_launch(void* const* d_in, const int* in_sizes, int n_in,
                              void* d_out, int out_size, void* d_ws, size_t ws_size,
                              hipStream_t stream) {
    const float* x = (const float*)d_in[0];
    const float* w = (const float*)d_in[1];
    float* out = (float*)d_out;

    if (ws_size >= XT_BYTES + WB_BYTES) {
        unsigned char* xt = (unsigned char*)d_ws;
        __bf16* wb = (__bf16*)(xt + XT_BYTES);
        wcvt_kernel<<<(WELEMS + 255) / 256, 256, 0, stream>>>(w, wb, WELEMS);
        xprep_kernel<<<PBLK, 256, 0, stream>>>(x, xt);
        conv_kernel<<<NBLK, 512, 0, stream>>>(xt, wb, out);
    } else {
        fb_conv_kernel<<<NBLK, 512, 0, stream>>>(x, w, out);
    }
}

// Round 5
// 99.809 us; speedup vs baseline: 1.0232x; 1.0007x over previous
//
#include <hip/hip_runtime.h>
#include <hip/hip_bf16.h>

typedef __bf16 bf16x8 __attribute__((ext_vector_type(8)));
typedef float  f32x4  __attribute__((ext_vector_type(4)));

#define HW       3136
#define IMG_W    56
#define IMG_H    56
#define XT_ROW_B 16384                     // 64 cols * 128ch * 2B
#define XT_IMG_B (58*XT_ROW_B)             // 950272
#define XT_BYTES ((size_t)32*XT_IMG_B)     // ~30.4 MB
#define WELEMS   (9*128*128)
#define WB_BYTES ((size_t)WELEMS*2)
#define NBLK     896                       // 32 img * 28 row-pairs
#define PBLK     (32*58)                   // prepass blocks

// ---- weight fp32 -> bf16 ----
__global__ __launch_bounds__(256) void wcvt_kernel(const float* __restrict__ w,
                                                   __bf16* __restrict__ wb, int n) {
    int i = blockIdx.x * 256 + threadIdx.x;
    if (i < n) wb[i] = (__bf16)w[i];
}

// ---- prepass: x [n][c][h][w] fp32 -> xt [n][58][64][128] bf16,
//      zero borders, XOR swizzle ((col&7) granules) baked into layout ----
__global__ __launch_bounds__(256) void xprep_kernel(const float* __restrict__ x,
                                                    unsigned char* __restrict__ xt) {
    __shared__ float ldsF[128 * 65];
    const int bid = blockIdx.x;
    const int swz = (bid & 7) * (PBLK / 8) + (bid >> 3);
    const int n = swz / 58, rt = swz - n * 58;
    unsigned char* row = xt + (size_t)n * XT_IMG_B + (size_t)rt * XT_ROW_B;
    const int t = threadIdx.x;

    if (rt == 0 || rt == 57) {            // zero border rows
        f32x4 z = {0.f, 0.f, 0.f, 0.f};
        #pragma unroll
        for (int i = 0; i < 4; ++i) *(f32x4*)(row + t * 64 + i * 16) = z;
        return;
    }
    const int r = rt - 1;
    const float* xr = x + (size_t)n * 128 * HW + (size_t)r * IMG_W;
    const int wv = t >> 6, lane = t & 63;
    const int wi = min(lane, IMG_W - 1);
    #pragma unroll
    for (int cc = 0; cc < 32; ++cc) {
        int c = cc * 4 + wv;
        float v = xr[(size_t)c * HW + wi];
        ldsF[c * 65 + lane] = (lane < IMG_W) ? v : 0.f;
    }
    __syncthreads();

    const int cl = t >> 2, q = t & 3;     // col 0..63, channel quarter
    const bool inb = (cl >= 1) && (cl <= 56);
    #pragma unroll
    for (int g4 = 0; g4 < 4; ++g4) {
        int gi = q * 4 + g4;              // granule = channels gi*8..gi*8+7
        bf16x8 pk;
        #pragma unroll
        for (int j = 0; j < 8; ++j)
            pk[j] = inb ? (__bf16)ldsF[(gi * 8 + j) * 65 + (cl - 1)] : (__bf16)0.0f;
        *(bf16x8*)(row + cl * 256 + ((gi ^ (cl & 7)) * 16)) = pk;
    }
}

// ---- conv: one wave = 32 oc x NPF*16 positions; A-frag 4-deep pipeline ----
template<int NPF>
__device__ __forceinline__ void compute_store(const unsigned char* xs, const __bf16* wb,
                                              float* on, int oc0, int pf0, int r0, int lane) {
    const int l15 = lane & 15, lq = lane >> 4;
    int rowb[NPF], scol[NPF], p_[NPF];
    #pragma unroll
    for (int k = 0; k < NPF; ++k) {
        int p = (pf0 + k) * 16 + l15;     // 0..111 block-local pos
        int pr = p / 56, pc = p - pr * 56;
        p_[k] = p;
        rowb[k] = (pr + 1) * 64 + (pc + 1);
        scol[k] = pc + 1;
    }
    f32x4 acc[2][NPF];
    #pragma unroll
    for (int f = 0; f < 2; ++f)
        #pragma unroll
        for (int k = 0; k < NPF; ++k) acc[f][k] = (f32x4){0.f, 0.f, 0.f, 0.f};

    const __bf16* wt0 = wb + (oc0 + l15) * 128 + lq * 8;

    // 4-deep A-fragment ring over 36 (tap,c) steps; all indices static after unroll.
    bf16x8 bufA[4], bufB[4];
    #pragma unroll
    for (int s = 0; s < 3; ++s) {         // steps 0..2 are tap 0, c = s
        bufA[s] = *(const bf16x8*)(wt0 + s * 32);
        bufB[s] = *(const bf16x8*)(wt0 + 2048 + s * 32);
    }

    #pragma unroll
    for (int tc = 0; tc < 36; ++tc) {
        const int tap = tc >> 2, c = tc & 3;
        if (tc + 3 < 36) {                // issue loads 3 steps ahead
            const int t2 = (tc + 3) >> 2, c2 = (tc + 3) & 3;
            bufA[(tc + 3) & 3] = *(const bf16x8*)(wt0 + t2 * 16384 + c2 * 32);
            bufB[(tc + 3) & 3] = *(const bf16x8*)(wt0 + t2 * 16384 + 2048 + c2 * 32);
        }
        const int dh = tap / 3 - 1, dw = tap - (tap / 3) * 3 - 1;
        #pragma unroll
        for (int k = 0; k < NPF; ++k) {
            int base = (rowb[k] + dh * 64 + dw) * 256;
            int sw   = (scol[k] + dw) & 7;
            int gi   = (c * 4 + lq) ^ sw;
            bf16x8 b = *(const bf16x8*)(xs + base + gi * 16);
            acc[0][k] = __builtin_amdgcn_mfma_f32_16x16x32_bf16(bufA[tc & 3], b, acc[0][k], 0, 0, 0);
            acc[1][k] = __builtin_amdgcn_mfma_f32_16x16x32_bf16(bufB[tc & 3], b, acc[1][k], 0, 0, 0);
        }
    }

    #pragma unroll
    for (int f = 0; f < 2; ++f)
        #pragma unroll
        for (int k = 0; k < NPF; ++k) {
            int pos = r0 * 56 + p_[k];
            int oc  = oc0 + f * 16 + lq * 4;
            #pragma unroll
            for (int rr = 0; rr < 4; ++rr)
                on[(size_t)(oc + rr) * HW + pos] = acc[f][k][rr];
        }
}

__global__ __launch_bounds__(512, 4) void conv_kernel(const unsigned char* __restrict__ xt,
                                                      const __bf16* __restrict__ wb,
                                                      float* __restrict__ out) {
    __shared__ __align__(16) unsigned char xs[65536];   // 4 rows x 64 cols x 256B
    const int t = threadIdx.x, lane = t & 63, wv = t >> 6;   // 8 waves
    const int bid = blockIdx.x;
    const int swz = (bid & 7) * (NBLK / 8) + (bid >> 3);
    const int n = swz / 28, rp = swz - n * 28, r0 = rp * 2;

    // async linear 64KB copy: xt rows r0..r0+3 (contiguous) -> LDS
    const unsigned char* src = xt + (size_t)n * XT_IMG_B + (size_t)r0 * XT_ROW_B;
    #pragma unroll
    for (int i = 0; i < 8; ++i) {
        __builtin_amdgcn_global_load_lds(
            (const __attribute__((address_space(1))) unsigned int*)(src + i * 8192 + t * 16),
            (__attribute__((address_space(3))) unsigned int*)(xs + i * 8192 + wv * 1024),
            16, 0, 0);
    }
    __syncthreads();

    // wave -> 32-oc quarter x pos-frag group: waves 0-3 frags 0-3, waves 4-7 frags 4-6
    const int oc0 = (wv & 3) * 32;
    float* on = out + (size_t)n * 128 * HW;
    if (wv < 4) compute_store<4>(xs, wb, on, oc0, 0, r0, lane);
    else        compute_store<3>(xs, wb, on, oc0, 4, r0, lane);
}

// ================= fallback (ws too small): self-contained, fp32 weights =================
#define PITCH  272
#define LDSB   (4*64*PITCH)

template<int NPF>
__device__ __forceinline__ void fb_compute(const unsigned char* xs, const float* wf,
                                           float* on, int oc0, int pf0, int r0, int lane) {
    const int l15 = lane & 15, lq = lane >> 4;
    int spb[NPF];
    #pragma unroll
    for (int k = 0; k < NPF; ++k) {
        int p = (pf0 + k) * 16 + l15;
        int r = p / 56, w = p - r * 56;
        spb[k] = ((r + 1) * 64 + (w + 1)) * PITCH + lq * 16;
    }
    f32x4 acc[2][NPF];
    #pragma unroll
    for (int f = 0; f < 2; ++f)
        #pragma unroll
        for (int k = 0; k < NPF; ++k) acc[f][k] = (f32x4){0.f, 0.f, 0.f, 0.f};
    #pragma unroll 3
    for (int tap = 0; tap < 9; ++tap) {
        const int offb  = ((tap / 3) * 64 + (tap % 3) - 65) * PITCH;
        const int wbase = tap * 16384 + oc0 * 128 + l15 * 128 + lq * 8;
        #pragma unroll
        for (int c = 0; c < 4; ++c) {
            bf16x8 a[2];
            #pragma unroll
            for (int f = 0; f < 2; ++f) {
                const float* p = wf + wbase + f * 2048 + c * 32;
                #pragma unroll
                for (int j = 0; j < 8; ++j) a[f][j] = (__bf16)p[j];
            }
            #pragma unroll
            for (int k = 0; k < NPF; ++k) {
                bf16x8 b = *(const bf16x8*)(xs + spb[k] + offb + c * 64);
                #pragma unroll
                for (int f = 0; f < 2; ++f)
                    acc[f][k] = __builtin_amdgcn_mfma_f32_16x16x32_bf16(a[f], b, acc[f][k], 0, 0, 0);
            }
        }
    }
    #pragma unroll
    for (int f = 0; f < 2; ++f)
        #pragma unroll
        for (int k = 0; k < NPF; ++k) {
            int pos = r0 * 56 + (pf0 + k) * 16 + l15;
            int oc  = oc0 + f * 16 + lq * 4;
            #pragma unroll
            for (int rr = 0; rr < 4; ++rr)
                on[(size_t)(oc + rr) * HW + pos] = acc[f][k][rr];
        }
}

__global__ __launch_bounds__(512, 4) void fb_conv_kernel(const float* __restrict__ x,
                                                         const float* __restrict__ wf,
                                                         float* __restrict__ out) {
    __shared__ __align__(16) unsigned char xs[LDSB];
    const int tid = threadIdx.x, lane = tid & 63, wv = tid >> 6;
    const int bid = blockIdx.x;
    const int swz = (bid & 7) * (NBLK / 8) + (bid >> 3);
    const int n = swz / 28, rp = swz - n * 28, r0 = rp * 2;
    if (wv < 4) {
        const float* xn = x + (size_t)n * 128 * HW;
        const int ar = r0 - 1 + wv, wi = lane - 1;
        const bool v = (ar >= 0) & (ar < IMG_H) & (wi >= 0) & (wi < IMG_W);
        const int gc = min(max(ar, 0), IMG_H - 1) * IMG_W + min(max(wi, 0), IMG_W - 1);
        unsigned char* dst = xs + (wv * 64 + lane) * PITCH;
        #pragma unroll
        for (int cg = 0; cg < 16; ++cg) {
            bf16x8 pk;
            #pragma unroll
            for (int j = 0; j < 8; ++j) {
                float f = xn[(size_t)(cg * 8 + j) * HW + gc];
                pk[j] = (__bf16)(v ? f : 0.f);
            }
            *(bf16x8*)(dst + cg * 16) = pk;
        }
    }
    __syncthreads();
    const int oc0 = (wv & 3) * 32;
    float* on = out + (size_t)n * 128 * HW;
    if (wv < 4) fb_compute<4>(xs, wf, on, oc0, 0, r0, lane);
    else        fb_compute<3>(xs, wf, on, oc0, 4, r0, lane);
}

extern "C" void kernel_launch(void* const* d_in, const int* in_sizes, int n_in,
                              void* d_out, int out_size, void* d_ws, size_t ws_size,
                              hipStream_t stream) {
    const float* x = (const float*)d_in[0];
    const float* w = (const float*)d_in[1];
    float* out = (float*)d_out;

    if (ws_size >= XT_BYTES + WB_BYTES) {
        unsigned char* xt = (unsigned char*)d_ws;
        __bf16* wb = (__bf16*)(xt + XT_BYTES);
        wcvt_kernel<<<(WELEMS + 255) / 256, 256, 0, stream>>>(w, wb, WELEMS);
        xprep_kernel<<<PBLK, 256, 0, stream>>>(x, xt);
        conv_kernel<<<NBLK, 512, 0, stream>>>(xt, wb, out);
    } else {
        fb_conv_kernel<<<NBLK, 512, 0, stream>>>(x, w, out);
    }
}

// Round 6
// 75.927 us; speedup vs baseline: 1.3451x; 1.3145x over previous
//
#include <hip/hip_runtime.h>
#include <hip/hip_bf16.h>

typedef __bf16 bf16x8 __attribute__((ext_vector_type(8)));
typedef float  f32x4  __attribute__((ext_vector_type(4)));

#define HW       3136
#define IMG_W    56
#define IMG_H    56
#define XT_ROW_B 16384                     // 64 cols * 128ch * 2B
#define XT_IMG_B (58*XT_ROW_B)             // 950272
#define XT_BYTES ((size_t)32*XT_IMG_B)     // ~30.4 MB
#define WELEMS   (9*128*128)
#define WB_BYTES ((size_t)WELEMS*2)
#define NBLK     896                       // 32 img * 28 row-pairs
#define PBLK     (32*58)                   // prepass blocks

// ---- weight fp32 -> bf16, [tap][oc][granule g ^ (oc&7)] swizzled layout ----
__global__ __launch_bounds__(256) void wcvt_kernel(const float* __restrict__ w,
                                                   unsigned char* __restrict__ wb) {
    int i = blockIdx.x * 256 + threadIdx.x;          // one 16B granule each
    if (i >= 9 * 128 * 16) return;
    const int g = i & 15, oct = i >> 4;              // oct = tap*128 + oc
    const int oc = oct & 127;
    const float* src = w + (size_t)oct * 128 + g * 8;
    bf16x8 v;
    #pragma unroll
    for (int j = 0; j < 8; ++j) v[j] = (__bf16)src[j];
    *(bf16x8*)(wb + (size_t)oct * 256 + (size_t)(g ^ (oc & 7)) * 16) = v;
}

// ---- prepass: x [n][c][h][w] fp32 -> xt [n][58][64][128] bf16,
//      zero borders, XOR swizzle ((col&7) granules) baked into layout ----
__global__ __launch_bounds__(256) void xprep_kernel(const float* __restrict__ x,
                                                    unsigned char* __restrict__ xt) {
    __shared__ float ldsF[128 * 65];
    const int bid = blockIdx.x;
    const int swz = (bid & 7) * (PBLK / 8) + (bid >> 3);
    const int n = swz / 58, rt = swz - n * 58;
    unsigned char* row = xt + (size_t)n * XT_IMG_B + (size_t)rt * XT_ROW_B;
    const int t = threadIdx.x;

    if (rt == 0 || rt == 57) {            // zero border rows
        f32x4 z = {0.f, 0.f, 0.f, 0.f};
        #pragma unroll
        for (int i = 0; i < 4; ++i) *(f32x4*)(row + t * 64 + i * 16) = z;
        return;
    }
    const int r = rt - 1;
    const float* xr = x + (size_t)n * 128 * HW + (size_t)r * IMG_W;
    const int wv = t >> 6, lane = t & 63;
    const int wi = min(lane, IMG_W - 1);
    #pragma unroll
    for (int cc = 0; cc < 32; ++cc) {
        int c = cc * 4 + wv;
        float v = xr[(size_t)c * HW + wi];
        ldsF[c * 65 + lane] = (lane < IMG_W) ? v : 0.f;
    }
    __syncthreads();

    const int cl = t >> 2, q = t & 3;     // col 0..63, channel quarter
    const bool inb = (cl >= 1) && (cl <= 56);
    #pragma unroll
    for (int g4 = 0; g4 < 4; ++g4) {
        int gi = q * 4 + g4;              // granule = channels gi*8..gi*8+7
        bf16x8 pk;
        #pragma unroll
        for (int j = 0; j < 8; ++j)
            pk[j] = inb ? (__bf16)ldsF[(gi * 8 + j) * 65 + (cl - 1)] : (__bf16)0.0f;
        *(bf16x8*)(row + cl * 256 + ((gi ^ (cl & 7)) * 16)) = pk;
    }
}

// ---- conv: T3/T4 double-buffered W-tap pipeline, counted vmcnt ----
__global__ __launch_bounds__(512, 2) void conv_kernel(const unsigned char* __restrict__ xt,
                                                      const unsigned char* __restrict__ wb,
                                                      float* __restrict__ out) {
    __shared__ __align__(16) unsigned char smem[131072];   // 64KB x + 2x32KB W
    unsigned char* xs = smem;
    unsigned char* wl[2] = { smem + 65536, smem + 98304 };

    const int t = threadIdx.x, lane = t & 63, wv = t >> 6;   // 8 waves
    const int l15 = lane & 15, lq = lane >> 4;
    const int bid = blockIdx.x;
    const int swz = (bid & 7) * (NBLK / 8) + (bid >> 3);
    const int n = swz / 28, rp = swz - n * 28, r0 = rp * 2;

    const int NPF = (wv < 4) ? 4 : 3;
    const int pf0 = (wv < 4) ? 0 : 4;
    const int oc0 = (wv & 3) * 32;

    // per-lane B addressing (block-local positions)
    int rowb[4], scol[4], p_[4];
    #pragma unroll
    for (int k = 0; k < 4; ++k) {
        int p = (pf0 + k) * 16 + l15;
        int pr = p / 56, pc = p - pr * 56;
        p_[k] = p;
        rowb[k] = (pr + 1) * 64 + (pc + 1);
        scol[k] = pc + 1;
    }

    // ---- prologue: stage x window (64KB) + W tap0 (32KB), drain, barrier ----
    const unsigned char* src = xt + (size_t)n * XT_IMG_B + (size_t)r0 * XT_ROW_B;
    #pragma unroll
    for (int i = 0; i < 8; ++i) {
        __builtin_amdgcn_global_load_lds(
            (const __attribute__((address_space(1))) unsigned int*)(src + i * 8192 + t * 16),
            (__attribute__((address_space(3))) unsigned int*)(xs + i * 8192 + wv * 1024),
            16, 0, 0);
    }
    #pragma unroll
    for (int i = 0; i < 4; ++i) {
        __builtin_amdgcn_global_load_lds(
            (const __attribute__((address_space(1))) unsigned int*)(wb + i * 8192 + t * 16),
            (__attribute__((address_space(3))) unsigned int*)(wl[0] + i * 8192 + wv * 1024),
            16, 0, 0);
    }
    asm volatile("s_waitcnt vmcnt(0)" ::: "memory");
    __builtin_amdgcn_sched_barrier(0);
    __builtin_amdgcn_s_barrier();
    __builtin_amdgcn_sched_barrier(0);

    f32x4 acc[2][4];
    #pragma unroll
    for (int f = 0; f < 2; ++f)
        #pragma unroll
        for (int k = 0; k < 4; ++k) acc[f][k] = (f32x4){0.f, 0.f, 0.f, 0.f};

    // ---- 9-tap pipeline, fully unrolled ----
    #pragma unroll
    for (int tap = 0; tap < 9; ++tap) {
        if (tap < 8) {                      // stage next tap into other buffer
            const unsigned char* ws = wb + (size_t)(tap + 1) * 32768;
            unsigned char* dst = wl[(tap + 1) & 1];
            #pragma unroll
            for (int i = 0; i < 4; ++i) {
                __builtin_amdgcn_global_load_lds(
                    (const __attribute__((address_space(1))) unsigned int*)(ws + i * 8192 + t * 16),
                    (__attribute__((address_space(3))) unsigned int*)(dst + i * 8192 + wv * 1024),
                    16, 0, 0);
            }
            asm volatile("s_waitcnt vmcnt(4)" ::: "memory");   // current tap's 4 done
        } else {
            asm volatile("s_waitcnt vmcnt(0)" ::: "memory");
        }
        __builtin_amdgcn_sched_barrier(0);
        __builtin_amdgcn_s_barrier();       // buf[tap&1] ready on all waves
        __builtin_amdgcn_sched_barrier(0);

        const unsigned char* wt = wl[tap & 1];
        const int dh = tap / 3 - 1, dw = tap - (tap / 3) * 3 - 1;
        int base[4], sw[4];
        #pragma unroll
        for (int k = 0; k < 4; ++k) {
            base[k] = (rowb[k] + dh * 64 + dw) * 256;
            sw[k]   = (scol[k] + dw) & 7;
        }

        __builtin_amdgcn_s_setprio(1);
        #pragma unroll
        for (int c = 0; c < 4; ++c) {
            const int agi = ((c * 4 + lq) ^ (l15 & 7)) * 16;
            bf16x8 a0 = *(const bf16x8*)(wt + (oc0 + l15) * 256 + agi);
            bf16x8 a1 = *(const bf16x8*)(wt + (oc0 + 16 + l15) * 256 + agi);
            #pragma unroll
            for (int k = 0; k < 4; ++k) {
                if (k < NPF) {
                    int gi = (c * 4 + lq) ^ sw[k];
                    bf16x8 b = *(const bf16x8*)(xs + base[k] + gi * 16);
                    acc[0][k] = __builtin_amdgcn_mfma_f32_16x16x32_bf16(a0, b, acc[0][k], 0, 0, 0);
                    acc[1][k] = __builtin_amdgcn_mfma_f32_16x16x32_bf16(a1, b, acc[1][k], 0, 0, 0);
                }
            }
        }
        __builtin_amdgcn_s_setprio(0);

        __builtin_amdgcn_sched_barrier(0);
        __builtin_amdgcn_s_barrier();       // all waves done reading buf[tap&1]
        __builtin_amdgcn_sched_barrier(0);
    }

    // ---- store ----
    float* on = out + (size_t)n * 128 * HW;
    #pragma unroll
    for (int f = 0; f < 2; ++f)
        #pragma unroll
        for (int k = 0; k < 4; ++k) {
            if (k < NPF) {
                int pos = r0 * 56 + p_[k];
                int oc  = oc0 + f * 16 + lq * 4;
                #pragma unroll
                for (int rr = 0; rr < 4; ++rr)
                    on[(size_t)(oc + rr) * HW + pos] = acc[f][k][rr];
            }
        }
}

// ================= fallback (ws too small): self-contained, fp32 weights =================
#define PITCH  272
#define LDSB   (4*64*PITCH)

template<int NPF>
__device__ __forceinline__ void fb_compute(const unsigned char* xs, const float* wf,
                                           float* on, int oc0, int pf0, int r0, int lane) {
    const int l15 = lane & 15, lq = lane >> 4;
    int spb[NPF];
    #pragma unroll
    for (int k = 0; k < NPF; ++k) {
        int p = (pf0 + k) * 16 + l15;
        int r = p / 56, w = p - r * 56;
        spb[k] = ((r + 1) * 64 + (w + 1)) * PITCH + lq * 16;
    }
    f32x4 acc[2][NPF];
    #pragma unroll
    for (int f = 0; f < 2; ++f)
        #pragma unroll
        for (int k = 0; k < NPF; ++k) acc[f][k] = (f32x4){0.f, 0.f, 0.f, 0.f};
    #pragma unroll 3
    for (int tap = 0; tap < 9; ++tap) {
        const int offb  = ((tap / 3) * 64 + (tap % 3) - 65) * PITCH;
        const int wbase = tap * 16384 + oc0 * 128 + l15 * 128 + lq * 8;
        #pragma unroll
        for (int c = 0; c < 4; ++c) {
            bf16x8 a[2];
            #pragma unroll
            for (int f = 0; f < 2; ++f) {
                const float* p = wf + wbase + f * 2048 + c * 32;
                #pragma unroll
                for (int j = 0; j < 8; ++j) a[f][j] = (__bf16)p[j];
            }
            #pragma unroll
            for (int k = 0; k < NPF; ++k) {
                bf16x8 b = *(const bf16x8*)(xs + spb[k] + offb + c * 64);
                #pragma unroll
                for (int f = 0; f < 2; ++f)
                    acc[f][k] = __builtin_amdgcn_mfma_f32_16x16x32_bf16(a[f], b, acc[f][k], 0, 0, 0);
            }
        }
    }
    #pragma unroll
    for (int f = 0; f < 2; ++f)
        #pragma unroll
        for (int k = 0; k < NPF; ++k) {
            int pos = r0 * 56 + (pf0 + k) * 16 + l15;
            int oc  = oc0 + f * 16 + lq * 4;
            #pragma unroll
            for (int rr = 0; rr < 4; ++rr)
                on[(size_t)(oc + rr) * HW + pos] = acc[f][k][rr];
        }
}

__global__ __launch_bounds__(512, 4) void fb_conv_kernel(const float* __restrict__ x,
                                                         const float* __restrict__ wf,
                                                         float* __restrict__ out) {
    __shared__ __align__(16) unsigned char xs[LDSB];
    const int tid = threadIdx.x, lane = tid & 63, wv = tid >> 6;
    const int bid = blockIdx.x;
    const int swz = (bid & 7) * (NBLK / 8) + (bid >> 3);
    const int n = swz / 28, rp = swz - n * 28, r0 = rp * 2;
    if (wv < 4) {
        const float* xn = x + (size_t)n * 128 * HW;
        const int ar = r0 - 1 + wv, wi = lane - 1;
        const bool v = (ar >= 0) & (ar < IMG_H) & (wi >= 0) & (wi < IMG_W);
        const int gc = min(max(ar, 0), IMG_H - 1) * IMG_W + min(max(wi, 0), IMG_W - 1);
        unsigned char* dst = xs + (wv * 64 + lane) * PITCH;
        #pragma unroll
        for (int cg = 0; cg < 16; ++cg) {
            bf16x8 pk;
            #pragma unroll
            for (int j = 0; j < 8; ++j) {
                float f = xn[(size_t)(cg * 8 + j) * HW + gc];
                pk[j] = (__bf16)(v ? f : 0.f);
            }
            *(bf16x8*)(dst + cg * 16) = pk;
        }
    }
    __syncthreads();
    const int oc0 = (wv & 3) * 32;
    float* on = out + (size_t)n * 128 * HW;
    if (wv < 4) fb_compute<4>(xs, wf, on, oc0, 0, r0, lane);
    else        fb_compute<3>(xs, wf, on, oc0, 4, r0, lane);
}

extern "C" void kernel_launch(void* const* d_in, const int* in_sizes, int n_in,
                              void* d_out, int out_size, void* d_ws, size_t ws_size,
                              hipStream_t stream) {
    const float* x = (const float*)d_in[0];
    const float* w = (const float*)d_in[1];
    float* out = (float*)d_out;

    if (ws_size >= XT_BYTES + WB_BYTES) {
        unsigned char* xt = (unsigned char*)d_ws;
        unsigned char* wb = xt + XT_BYTES;
        wcvt_kernel<<<(9 * 128 * 16 + 255) / 256, 256, 0, stream>>>(w, wb);
        xprep_kernel<<<PBLK, 256, 0, stream>>>(x, xt);
        conv_kernel<<<NBLK, 512, 0, stream>>>(xt, wb, out);
    } else {
        fb_conv_kernel<<<NBLK, 512, 0, stream>>>(x, w, out);
    }
}

// Round 7
// 63.366 us; speedup vs baseline: 1.6117x; 1.1982x over previous
//
#include <hip/hip_runtime.h>
#include <hip/hip_bf16.h>

typedef __bf16 bf16x8 __attribute__((ext_vector_type(8)));
typedef float  f32x4  __attribute__((ext_vector_type(4)));

#define HW       3136
#define IMG_W    56
#define IMG_H    56
#define XT_ROW_B 16384                     // 64 cols * 128ch * 2B
#define XT_IMG_B (58*XT_ROW_B)             // 950272
#define XT_BYTES ((size_t)32*XT_IMG_B)     // ~30.4 MB
#define WGRAN    (9*128*16)                // 16B granules in W
#define WB_BYTES ((size_t)WGRAN*16)        // 294912
#define NBLK     896                       // 32 img * 28 row-pairs
#define PBLK     (32*58)                   // prepass blocks

// ---- weight fp32 -> bf16, fragment-major layout:
//      [tap][q32][c][f][lq][l15] granules of 16B, so a wave's 8 A-frags for
//      one tap are 8 contiguous-1KB wave-loads at lane*16 + (c*2+f)*1024 ----
__global__ __launch_bounds__(256) void wcvt_kernel(const float* __restrict__ w,
                                                   unsigned char* __restrict__ wb) {
    int i = blockIdx.x * 256 + threadIdx.x;          // one 16B granule each
    if (i >= WGRAN) return;
    const int l15 = i & 15, lq = (i >> 4) & 3, f = (i >> 6) & 1;
    const int c   = (i >> 7) & 3, q32 = (i >> 9) & 3, tap = i >> 11;
    const int oc = q32 * 32 + f * 16 + l15;
    const int ch = c * 32 + lq * 8;
    const float* src = w + (size_t)(tap * 128 + oc) * 128 + ch;
    bf16x8 v;
    #pragma unroll
    for (int j = 0; j < 8; ++j) v[j] = (__bf16)src[j];
    *(bf16x8*)(wb + (size_t)i * 16) = v;
}

// ---- prepass: x [n][c][h][w] fp32 -> xt [n][58][64][128] bf16,
//      zero borders, XOR swizzle ((col&7) granules) baked into layout ----
__global__ __launch_bounds__(256) void xprep_kernel(const float* __restrict__ x,
                                                    unsigned char* __restrict__ xt) {
    __shared__ float ldsF[128 * 65];
    const int bid = blockIdx.x;
    const int swz = (bid & 7) * (PBLK / 8) + (bid >> 3);
    const int n = swz / 58, rt = swz - n * 58;
    unsigned char* row = xt + (size_t)n * XT_IMG_B + (size_t)rt * XT_ROW_B;
    const int t = threadIdx.x;

    if (rt == 0 || rt == 57) {            // zero border rows
        f32x4 z = {0.f, 0.f, 0.f, 0.f};
        #pragma unroll
        for (int i = 0; i < 4; ++i) *(f32x4*)(row + t * 64 + i * 16) = z;
        return;
    }
    const int r = rt - 1;
    const float* xr = x + (size_t)n * 128 * HW + (size_t)r * IMG_W;
    const int wv = t >> 6, lane = t & 63;
    const int wi = min(lane, IMG_W - 1);
    #pragma unroll
    for (int cc = 0; cc < 32; ++cc) {
        int c = cc * 4 + wv;
        float v = xr[(size_t)c * HW + wi];
        ldsF[c * 65 + lane] = (lane < IMG_W) ? v : 0.f;
    }
    __syncthreads();

    const int cl = t >> 2, q = t & 3;     // col 0..63, channel quarter
    const bool inb = (cl >= 1) && (cl <= 56);
    #pragma unroll
    for (int g4 = 0; g4 < 4; ++g4) {
        int gi = q * 4 + g4;              // granule = channels gi*8..gi*8+7
        bf16x8 pk;
        #pragma unroll
        for (int j = 0; j < 8; ++j)
            pk[j] = inb ? (__bf16)ldsF[(gi * 8 + j) * 65 + (cl - 1)] : (__bf16)0.0f;
        *(bf16x8*)(row + cl * 256 + ((gi ^ (cl & 7)) * 16)) = pk;
    }
}

// ---- conv: A double-buffered in registers (1 tap ahead), sched_barrier-pinned ----
template<int NPF>
__device__ __forceinline__ void compute_store(const unsigned char* xs, const __bf16* wt,
                                              float* on, int oc0, int pf0, int r0, int lane) {
    const int l15 = lane & 15, lq = lane >> 4;
    int vb[NPF], scol[NPF];
    #pragma unroll
    for (int k = 0; k < NPF; ++k) {
        int p = (pf0 + k) * 16 + l15;     // 0..111 block-local pos
        int pr = p / 56, pc = p - pr * 56;
        vb[k]   = ((pr + 1) * 64 + (pc + 1)) * 256;
        scol[k] = pc + 1;
    }
    f32x4 acc[2][NPF];
    #pragma unroll
    for (int f = 0; f < 2; ++f)
        #pragma unroll
        for (int k = 0; k < NPF; ++k) acc[f][k] = (f32x4){0.f, 0.f, 0.f, 0.f};

    // A register double-buffer: aB[buf][f*4+c], buf/tap indices static after unroll
    bf16x8 aB[2][8];
    #pragma unroll
    for (int i = 0; i < 8; ++i)
        aB[0][i] = *(const bf16x8*)(wt + ((i & 3) * 2 + (i >> 2)) * 512);

    #pragma unroll
    for (int tap = 0; tap < 9; ++tap) {
        if (tap < 8) {                    // issue next tap's 8 frag loads (1KB coalesced each)
            const __bf16* wn = wt + (tap + 1) * 16384;
            #pragma unroll
            for (int i = 0; i < 8; ++i)
                aB[(tap + 1) & 1][i] = *(const bf16x8*)(wn + ((i & 3) * 2 + (i >> 2)) * 512);
        }
        __builtin_amdgcn_sched_barrier(0);   // pin load-issue before the MFMA cluster

        const int dh = tap / 3 - 1, dw = tap - (tap / 3) * 3 - 1;
        int base[NPF], sw[NPF];
        #pragma unroll
        for (int k = 0; k < NPF; ++k) {
            base[k] = vb[k] + (dh * 64 + dw) * 256;
            sw[k]   = (scol[k] + dw) & 7;
        }
        __builtin_amdgcn_s_setprio(1);
        #pragma unroll
        for (int c = 0; c < 4; ++c) {
            #pragma unroll
            for (int k = 0; k < NPF; ++k) {
                int gi = ((c * 4 + lq) ^ sw[k]) * 16;
                bf16x8 b = *(const bf16x8*)(xs + base[k] + gi);
                acc[0][k] = __builtin_amdgcn_mfma_f32_16x16x32_bf16(aB[tap & 1][c],     b, acc[0][k], 0, 0, 0);
                acc[1][k] = __builtin_amdgcn_mfma_f32_16x16x32_bf16(aB[tap & 1][4 + c], b, acc[1][k], 0, 0, 0);
            }
        }
        __builtin_amdgcn_s_setprio(0);
        __builtin_amdgcn_sched_barrier(0);   // keep next iteration's loads out of this cluster
    }

    #pragma unroll
    for (int f = 0; f < 2; ++f)
        #pragma unroll
        for (int k = 0; k < NPF; ++k) {
            int pos = r0 * 56 + (pf0 + k) * 16 + l15;
            int oc  = oc0 + f * 16 + lq * 4;
            #pragma unroll
            for (int rr = 0; rr < 4; ++rr)
                on[(size_t)(oc + rr) * HW + pos] = acc[f][k][rr];
        }
}

__global__ __launch_bounds__(512, 4) void conv_kernel(const unsigned char* __restrict__ xt,
                                                      const unsigned char* __restrict__ wb,
                                                      float* __restrict__ out) {
    __shared__ __align__(16) unsigned char xs[65536];   // 4 rows x 64 cols x 256B
    const int t = threadIdx.x, lane = t & 63, wv = t >> 6;   // 8 waves
    const int bid = blockIdx.x;
    const int swz = (bid & 7) * (NBLK / 8) + (bid >> 3);
    const int n = swz / 28, rp = swz - n * 28, r0 = rp * 2;

    // async linear 64KB copy: xt rows r0..r0+3 (contiguous) -> LDS
    const unsigned char* src = xt + (size_t)n * XT_IMG_B + (size_t)r0 * XT_ROW_B;
    #pragma unroll
    for (int i = 0; i < 8; ++i) {
        __builtin_amdgcn_global_load_lds(
            (const __attribute__((address_space(1))) unsigned int*)(src + i * 8192 + t * 16),
            (__attribute__((address_space(3))) unsigned int*)(xs + i * 8192 + wv * 1024),
            16, 0, 0);
    }
    __syncthreads();

    const int oc0 = (wv & 3) * 32;
    // per-wave lane base into fragment-major W: [tap][q32][1KB frag][lane*16]
    const __bf16* wt = (const __bf16*)(wb + (size_t)(wv & 3) * 8192 + lane * 16);
    float* on = out + (size_t)n * 128 * HW;
    if (wv < 4) compute_store<4>(xs, wt, on, oc0, 0, r0, lane);
    else        compute_store<3>(xs, wt, on, oc0, 4, r0, lane);
}

// ================= fallback (ws too small): self-contained, fp32 weights =================
#define PITCH  272
#define LDSB   (4*64*PITCH)

template<int NPF>
__device__ __forceinline__ void fb_compute(const unsigned char* xs, const float* wf,
                                           float* on, int oc0, int pf0, int r0, int lane) {
    const int l15 = lane & 15, lq = lane >> 4;
    int spb[NPF];
    #pragma unroll
    for (int k = 0; k < NPF; ++k) {
        int p = (pf0 + k) * 16 + l15;
        int r = p / 56, w = p - r * 56;
        spb[k] = ((r + 1) * 64 + (w + 1)) * PITCH + lq * 16;
    }
    f32x4 acc[2][NPF];
    #pragma unroll
    for (int f = 0; f < 2; ++f)
        #pragma unroll
        for (int k = 0; k < NPF; ++k) acc[f][k] = (f32x4){0.f, 0.f, 0.f, 0.f};
    #pragma unroll 3
    for (int tap = 0; tap < 9; ++tap) {
        const int offb  = ((tap / 3) * 64 + (tap % 3) - 65) * PITCH;
        const int wbase = tap * 16384 + oc0 * 128 + l15 * 128 + lq * 8;
        #pragma unroll
        for (int c = 0; c < 4; ++c) {
            bf16x8 a[2];
            #pragma unroll
            for (int f = 0; f < 2; ++f) {
                const float* p = wf + wbase + f * 2048 + c * 32;
                #pragma unroll
                for (int j = 0; j < 8; ++j) a[f][j] = (__bf16)p[j];
            }
            #pragma unroll
            for (int k = 0; k < NPF; ++k) {
                bf16x8 b = *(const bf16x8*)(xs + spb[k] + offb + c * 64);
                #pragma unroll
                for (int f = 0; f < 2; ++f)
                    acc[f][k] = __builtin_amdgcn_mfma_f32_16x16x32_bf16(a[f], b, acc[f][k], 0, 0, 0);
            }
        }
    }
    #pragma unroll
    for (int f = 0; f < 2; ++f)
        #pragma unroll
        for (int k = 0; k < NPF; ++k) {
            int pos = r0 * 56 + (pf0 + k) * 16 + l15;
            int oc  = oc0 + f * 16 + lq * 4;
            #pragma unroll
            for (int rr = 0; rr < 4; ++rr)
                on[(size_t)(oc + rr) * HW + pos] = acc[f][k][rr];
        }
}

__global__ __launch_bounds__(512, 4) void fb_conv_kernel(const float* __restrict__ x,
                                                         const float* __restrict__ wf,
                                                         float* __restrict__ out) {
    __shared__ __align__(16) unsigned char xs[LDSB];
    const int tid = threadIdx.x, lane = tid & 63, wv = tid >> 6;
    const int bid = blockIdx.x;
    const int swz = (bid & 7) * (NBLK / 8) + (bid >> 3);
    const int n = swz / 28, rp = swz - n * 28, r0 = rp * 2;
    if (wv < 4) {
        const float* xn = x + (size_t)n * 128 * HW;
        const int ar = r0 - 1 + wv, wi = lane - 1;
        const bool v = (ar >= 0) & (ar < IMG_H) & (wi >= 0) & (wi < IMG_W);
        const int gc = min(max(ar, 0), IMG_H - 1) * IMG_W + min(max(wi, 0), IMG_W - 1);
        unsigned char* dst = xs + (wv * 64 + lane) * PITCH;
        #pragma unroll
        for (int cg = 0; cg < 16; ++cg) {
            bf16x8 pk;
            #pragma unroll
            for (int j = 0; j < 8; ++j) {
                float f = xn[(size_t)(cg * 8 + j) * HW + gc];
                pk[j] = (__bf16)(v ? f : 0.f);
            }
            *(bf16x8*)(dst + cg * 16) = pk;
        }
    }
    __syncthreads();
    const int oc0 = (wv & 3) * 32;
    float* on = out + (size_t)n * 128 * HW;
    if (wv < 4) fb_compute<4>(xs, wf, on, oc0, 0, r0, lane);
    else        fb_compute<3>(xs, wf, on, oc0, 4, r0, lane);
}

extern "C" void kernel_launch(void* const* d_in, const int* in_sizes, int n_in,
                              void* d_out, int out_size, void* d_ws, size_t ws_size,
                              hipStream_t stream) {
    const float* x = (const float*)d_in[0];
    const float* w = (const float*)d_in[1];
    float* out = (float*)d_out;

    if (ws_size >= XT_BYTES + WB_BYTES) {
        unsigned char* xt = (unsigned char*)d_ws;
        unsigned char* wb = xt + XT_BYTES;
        wcvt_kernel<<<(WGRAN + 255) / 256, 256, 0, stream>>>(w, wb);
        xprep_kernel<<<PBLK, 256, 0, stream>>>(x, xt);
        conv_kernel<<<NBLK, 512, 0, stream>>>(xt, wb, out);
    } else {
        fb_conv_kernel<<<NBLK, 512, 0, stream>>>(x, w, out);
    }
}